// Round 7
// baseline (347.152 us; speedup 1.0000x reference)
//
#include <hip/hip_runtime.h>
#include <hip/hip_fp16.h>
#include <math.h>

#define NATOMS 65536

typedef _Float16 f16_t;
typedef __attribute__((ext_vector_type(8))) _Float16 half8;
typedef __attribute__((ext_vector_type(4))) float f32x4;

__constant__ int c_offs[12] = {0,1536,9728,26112,50688,62976,64000,64512,65024,65280,65408,65536};

struct Adj { const int* p[10]; };

__device__ __forceinline__ int seg_of(int row) {
    int s = 0;
#pragma unroll
    for (int i = 1; i <= 10; ++i) s += (row >= c_offs[i]) ? 1 : 0;
    return s;
}

// async global -> LDS, 16 B per lane; LDS dst = wave-uniform base + lane*16
__device__ __forceinline__ void glds16(const f16_t* g, f16_t* l) {
    __builtin_amdgcn_global_load_lds(
        (const __attribute__((address_space(1))) unsigned int*)g,
        (__attribute__((address_space(3))) unsigned int*)l,
        16, 0, 0);
}

// packed f16 max (exact)
__device__ __forceinline__ half8 max8(half8 a, half8 b) {
    half8 r;
#pragma unroll
    for (int e = 0; e < 8; ++e) r[e] = (a[e] >= b[e]) ? a[e] : b[e];
    return r;
}

// Blob layout (MFMA A-fragment order), NKB = cols/32:
//   addr(r,k) = ((r>>4)*NKB + (k>>5))*512 + ((k>>3)&3)*128 + (r&15)*8 + (k&7)
// Key identity: chunk*512 + lane*8 IS the per-lane MFMA fragment -> blob tensors
// can be loaded global->VGPR directly (no LDS round-trip).

// ---------------- merged: weight packing (+ counts zeroing) + cvt_pad ----------------
__global__ void pack_cvt(const float* __restrict__ g1w0, const float* __restrict__ g1ws,
                         const float* __restrict__ g1wn,
                         const float* __restrict__ g2w0, const float* __restrict__ g2ws,
                         const float* __restrict__ g2wn,
                         const float* __restrict__ dw, const float* __restrict__ ow,
                         f16_t* __restrict__ W1p, f16_t* __restrict__ W2p,
                         f16_t* __restrict__ Wdp, f16_t* __restrict__ Wop,
                         int* __restrict__ counts,
                         const float* __restrict__ xf, f16_t* __restrict__ xq) {
    if (blockIdx.x >= 8384) {
        int idx = (blockIdx.x - 8384) * 256 + threadIdx.x;   // 65536*12 exact
        int r = idx / 12;
        int cc = idx - r * 12;
        int c = cc << 3;
        f16_t o[8];
#pragma unroll
        for (int e = 0; e < 8; ++e)
            o[e] = (c + e < 75) ? (f16_t)xf[(size_t)r*75 + c + e] : (f16_t)0.f;
        *(uint4*)(xq + (size_t)r*96 + c) = *(uint4*)o;
        return;
    }
    int idx = blockIdx.x * 256 + threadIdx.x;   // 8384*256 = 2146304 exact
    if (idx < 2048) counts[idx] = 0;
    if (idx < 540672) {
        int j = idx & 7, lane = (idx >> 3) & 63;
        int kb = (idx >> 9) % 6;
        int rest = idx / (512 * 6);
        int ni = rest & 15, s = rest >> 4;
        int k = kb * 32 + (lane >> 4) * 8 + j;
        int n = ni * 16 + (lane & 15);
        float v = 0.f;
        if (k < 75) v = (s == 0) ? g1w0[k*256 + n] : g1ws[((s-1)*75 + k)*256 + n];
        else if (k >= 96 && k < 171 && s > 0) v = g1wn[((s-1)*75 + (k-96))*256 + n];
        W1p[idx] = (f16_t)v;
    } else if (idx < 1982464) {
        int i2 = idx - 540672;
        int j = i2 & 7, lane = (i2 >> 3) & 63;
        int kb = (i2 >> 9) & 15;
        int rest = i2 >> 13;
        int ni = rest & 15, s = rest >> 4;
        int k = kb * 32 + (lane >> 4) * 8 + j;
        int n = ni * 16 + (lane & 15);
        float v = 0.f;
        if (k < 256) v = (s == 0) ? g2w0[k*256 + n] : g2ws[((s-1)*256 + k)*256 + n];
        else if (s > 0) v = g2wn[((s-1)*256 + (k-256))*256 + n];
        W2p[i2] = (f16_t)v;
    } else if (idx < 2113536) {
        int i2 = idx - 1982464;
        int j = i2 & 7, lane = (i2 >> 3) & 63;
        int kb = (i2 >> 9) & 7;
        int ni = (i2 >> 12) & 31;
        int k = kb * 32 + (lane >> 4) * 8 + j;
        int n = ni * 16 + (lane & 15);
        Wdp[i2] = (f16_t)dw[(size_t)k*512 + n];
    } else {
        int i2 = idx - 2113536;
        int j = i2 & 7, lane = (i2 >> 3) & 63;
        int kb = (i2 >> 9) & 31;
        int ni = i2 >> 14;
        int k = kb * 32 + (lane >> 4) * 8 + j;
        int n = ni * 16 + (lane & 15);
        Wop[i2] = (n < 24) ? (f16_t)ow[k*24 + n] : (f16_t)0.f;
    }
}

// ---------------- compile-time-degree gather helpers (row-major sources) ----------------
template<int D, int LD>
__device__ __forceinline__ void gathD(float* v, const f16_t* __restrict__ src,
                                      const int* __restrict__ ap, int c) {
    int rows[D];
#pragma unroll
    for (int j = 0; j < D; ++j) rows[j] = ap[j];
    uint4 raw[D];
#pragma unroll
    for (int j = 0; j < D; ++j) raw[j] = *(const uint4*)(src + (size_t)rows[j]*LD + c);
#pragma unroll
    for (int j = 0; j < D; ++j) {
        const f16_t* u = (const f16_t*)&raw[j];
#pragma unroll
        for (int e = 0; e < 8; ++e) v[e] += (float)u[e];
    }
}

template<int LD>
__device__ __forceinline__ void gath_sum(float* v, const f16_t* __restrict__ src,
                                         const int* __restrict__ ap, int s, int c) {
    switch (s) {
        case 1:  gathD<1,LD>(v,src,ap,c);  break;
        case 2:  gathD<2,LD>(v,src,ap,c);  break;
        case 3:  gathD<3,LD>(v,src,ap,c);  break;
        case 4:  gathD<4,LD>(v,src,ap,c);  break;
        case 5:  gathD<5,LD>(v,src,ap,c);  break;
        case 6:  gathD<6,LD>(v,src,ap,c);  break;
        case 7:  gathD<7,LD>(v,src,ap,c);  break;
        case 8:  gathD<8,LD>(v,src,ap,c);  break;
        case 9:  gathD<9,LD>(v,src,ap,c);  break;
        case 10: gathD<10,LD>(v,src,ap,c); break;
        default: break;
    }
}

template<int D, int LD>
__device__ __forceinline__ void gathD_pk(half8& v, const f16_t* __restrict__ src,
                                         const int* __restrict__ ap, int c) {
    int rows[D];
#pragma unroll
    for (int j = 0; j < D; ++j) rows[j] = ap[j];
    half8 raw[D];
#pragma unroll
    for (int j = 0; j < D; ++j) raw[j] = *(const half8*)(src + (size_t)rows[j]*LD + c);
#pragma unroll
    for (int j = 0; j < D; ++j) v = max8(v, raw[j]);
}

template<int LD>
__device__ __forceinline__ void gath_max(half8& v, const f16_t* __restrict__ src,
                                         const int* __restrict__ ap, int s, int c) {
    switch (s) {
        case 1:  gathD_pk<1,LD>(v,src,ap,c);  break;
        case 2:  gathD_pk<2,LD>(v,src,ap,c);  break;
        case 3:  gathD_pk<3,LD>(v,src,ap,c);  break;
        case 4:  gathD_pk<4,LD>(v,src,ap,c);  break;
        case 5:  gathD_pk<5,LD>(v,src,ap,c);  break;
        case 6:  gathD_pk<6,LD>(v,src,ap,c);  break;
        case 7:  gathD_pk<7,LD>(v,src,ap,c);  break;
        case 8:  gathD_pk<8,LD>(v,src,ap,c);  break;
        case 9:  gathD_pk<9,LD>(v,src,ap,c);  break;
        case 10: gathD_pk<10,LD>(v,src,ap,c); break;
        default: break;
    }
}

// ---------------- merged: NBX = sum_neigh xq (BLOB NKB=3)  +  segment scatter ----------------
__global__ __launch_bounds__(256) void nbsum_sc(const f16_t* __restrict__ xq,
                                                f16_t* __restrict__ NBX, Adj adj,
                                                const int* __restrict__ mem,
                                                int* __restrict__ counts,
                                                int* __restrict__ slots) {
    if (blockIdx.x >= 3072) {
        int i = (blockIdx.x - 3072) * 256 + threadIdx.x;   // 65536 exact
        int s = mem[i];
        int p = atomicAdd(&counts[s], 1);
        if (p < 32) slots[s*32 + p] = i;
        return;
    }
    int idx = blockIdx.x * 256 + threadIdx.x;   // 65536*12 exact, dense
    int r = (int)((unsigned)idx / 12u);
    int cc = idx - r * 12;
    int c = cc << 3;
    int s = seg_of(r);
    float v[8];
#pragma unroll
    for (int e = 0; e < 8; ++e) v[e] = 0.f;
    if (s > 0)
        gath_sum<96>(v, xq, adj.p[s-1] + (size_t)(r - c_offs[s]) * s, s, c);
    f16_t o[8];
#pragma unroll
    for (int e = 0; e < 8; ++e) o[e] = (f16_t)v[e];
    *(uint4*)(NBX + (size_t)(r>>4)*1536 + (c>>5)*512 + ((c>>3)&3)*128 + (r&15)*8) = *(uint4*)o;
}

// ---------------- graph pool: max over self+neighbors; packed f16; output rm or blob ----------------
template<bool BLOB>
__global__ __launch_bounds__(256) void pool_k(const f16_t* __restrict__ H,
                                              f16_t* __restrict__ P, Adj adj) {
    int idx = blockIdx.x * 256 + threadIdx.x;   // 65536*32 exact
    int r = idx >> 5;
    int c = (idx & 31) << 3;
    int s = seg_of(r);
    half8 v = *(const half8*)(H + (size_t)r*256 + c);
    if (s > 0)
        gath_max<256>(v, H, adj.p[s-1] + (size_t)(r - c_offs[s]) * s, s, c);
    if (BLOB)
        *(half8*)(P + (size_t)(r>>4)*4096 + (c>>5)*512 + ((c>>3)&3)*128 + (r&15)*8) = v;
    else
        *(half8*)(P + (size_t)r*256 + c) = v;
}

// ---------------- neighbor-sum of pooled features (reads rm, writes BLOB NKB=8) ----------------
__global__ __launch_bounds__(256) void nbsum_k(const f16_t* __restrict__ P,
                                               f16_t* __restrict__ NB, Adj adj) {
    int idx = blockIdx.x * 256 + threadIdx.x;   // 65536*32 exact
    int r = idx >> 5;
    int c = (idx & 31) << 3;
    int s = seg_of(r);
    float v[8];
#pragma unroll
    for (int e = 0; e < 8; ++e) v[e] = 0.f;
    if (s > 0)
        gath_sum<256>(v, P, adj.p[s-1] + (size_t)(r - c_offs[s]) * s, s, c);
    f16_t o[8];
#pragma unroll
    for (int e = 0; e < 8; ++e) o[e] = (f16_t)v[e];
    *(uint4*)(NB + (size_t)(r>>4)*4096 + (c>>5)*512 + ((c>>3)&3)*128 + (r&15)*8) = *(uint4*)o;
}

// ---------------- 256x256-tile 8-wave f16 MFMA GEMM, BK=32 dbuf (gc1/gc2) ----------------
template<int NKB, int KSPB, int LDA, int NKBA1, int NY, int N, bool SEG>
__global__ __launch_bounds__(512, 2)
void gemm256(const f16_t* __restrict__ A0, const f16_t* __restrict__ A1,
             const f16_t* __restrict__ Wp,
             const float* __restrict__ bias,
             const float* __restrict__ bng, const float* __restrict__ bnb,
             const float* __restrict__ bnm, const float* __restrict__ bnv,
             f16_t* __restrict__ C)
{
    constexpr int NT  = NKB;                  // K-tiles of 32
    constexpr int NNT = N / 16;
    __shared__ f16_t sm[32768];               // 2 x 32 KB

    const int t = threadIdx.x;
    const int lane = t & 63, w = t >> 6;
    const int wm = w >> 2, wn = w & 3;        // 2M x 4N waves
    const int quad = lane >> 4, l16 = lane & 15;
    const int id = blockIdx.x;
    const int xi = id / NY, y = id - xi * NY;
    const int r0 = xi * 256;
    const int n0 = y * 256;
    const int rtg = r0 >> 4;
    const int nbase = n0 >> 4;
    const int segB = SEG ? seg_of(r0) : 0;
    const bool strad = SEG && (seg_of(r0 + 255) != segB);
    const int segw = SEG ? seg_of(r0 + wm*128) : 0;

    f32x4 acc[8][4];
#pragma unroll
    for (int mi = 0; mi < 8; ++mi)
#pragma unroll
        for (int ni = 0; ni < 4; ++ni) acc[mi][ni] = (f32x4){0.f,0.f,0.f,0.f};

    size_t aoff[2];
#pragma unroll
    for (int i = 0; i < 2; ++i)
        aoff[i] = (size_t)(r0 + (w*2 + i)*16 + l16) * LDA + quad*8;

    auto stage = [&](int kb, int buf) {
        f16_t* bb = sm + buf*16384;
#pragma unroll
        for (int i = 0; i < 2; ++i) {
            const int rt = w*2 + i;
            if constexpr (KSPB > 0) {
                if (kb < KSPB)
                    glds16(A0 + (size_t)kb*32 + aoff[i], bb + rt*512);
                else
                    glds16(A1 + ((size_t)(rtg + rt)*NKBA1 + (kb - KSPB))*512 + lane*8,
                           bb + rt*512);
            } else {
                glds16(A1 + ((size_t)(rtg + rt)*NKBA1 + kb)*512 + lane*8,
                       bb + rt*512);
            }
            glds16(Wp + ((size_t)(segB*NNT + nbase + rt)*NKB + kb)*512 + lane*8,
                   bb + 8192 + rt*512);
        }
    };

    stage(0, 0);
    __syncthreads();

    for (int kt = 0; kt < NT; ++kt) {
        const int buf = kt & 1;
        if (kt + 1 < NT) stage(kt + 1, buf ^ 1);    // prefetch overlaps compute
        const f16_t* bb = sm + buf*16384;

        half8 bfr[4];
        if (strad) {
#pragma unroll
            for (int ni = 0; ni < 4; ++ni)
                bfr[ni] = *(const half8*)(Wp +
                    ((size_t)(segw*NNT + nbase + wn*4 + ni)*NKB + kt)*512 + lane*8);
        } else {
#pragma unroll
            for (int ni = 0; ni < 4; ++ni)
                bfr[ni] = *(const half8*)(bb + 8192 + (wn*4 + ni)*512 + lane*8);
        }

#pragma unroll
        for (int ph = 0; ph < 4; ++ph) {
            half8 a[2];
#pragma unroll
            for (int m2 = 0; m2 < 2; ++m2)
                a[m2] = *(const half8*)(bb + (wm*8 + ph*2 + m2)*512 + lane*8);
#pragma unroll
            for (int m2 = 0; m2 < 2; ++m2)
#pragma unroll
                for (int ni = 0; ni < 4; ++ni)
                    acc[ph*2 + m2][ni] = __builtin_amdgcn_mfma_f32_16x16x32_f16(
                        a[m2], bfr[ni], acc[ph*2 + m2][ni], 0, 0, 0);
        }
        __syncthreads();
    }

    // epilogue: 4 strips of 64 rows via LDS, coalesced 16-B stores
    f16_t* eps = sm;
#pragma unroll
    for (int s = 0; s < 4; ++s) {
        if (wm == (s >> 1)) {
#pragma unroll
            for (int ni = 0; ni < 4; ++ni) {
                const int lcol = wn*64 + ni*16 + l16;
                const int col = n0 + lcol;
                const float scale = bng[col] * rsqrtf(bnv[col] + 1e-3f);
                const float shift = bnb[col] - bnm[col] * scale;
                const float bv = bias[(SEG ? segw*N : 0) + col];
#pragma unroll
                for (int m2 = 0; m2 < 4; ++m2) {
                    const int mi = (s & 1)*4 + m2;
                    const int rowb = m2*16 + quad*4;
#pragma unroll
                    for (int rr = 0; rr < 4; ++rr) {
                        float v = acc[mi][ni][rr] + bv;
                        v = fmaxf(v, 0.f);
                        v = fmaf(v, scale, shift);
                        eps[(rowb + rr)*264 + lcol] = (f16_t)v;
                    }
                }
            }
        }
        __syncthreads();
#pragma unroll
        for (int k = 0; k < 4; ++k) {
            int idx = k*512 + t;                    // 2048 uint4 = 64 rows x 32 chunks
            int row = idx >> 5, ch = idx & 31;
            *(uint4*)(C + (size_t)(r0 + s*64 + row)*N + n0 + ch*8) =
                *(const uint4*)&eps[row*264 + ch*8];
        }
        __syncthreads();
    }
}

// ---------------- dense GEMM: direct blob->register, ZERO K-loop LDS/barriers ----------------
// A blob NKB=8 (P2bl), B = Wdp blob (L2-resident). Each wave = independent 64x64 tile
// streaming fragments straight to VGPRs (chunk*512 + lane*8 IS the fragment).
// Ascending-kb accumulation -> bitwise-same C as staged version.
__global__ __launch_bounds__(256, 4)
void gemm_dir(const f16_t* __restrict__ A, const f16_t* __restrict__ Wp,
              const float* __restrict__ bias,
              const float* __restrict__ bng, const float* __restrict__ bnb,
              const float* __restrict__ bnm, const float* __restrict__ bnv,
              f16_t* __restrict__ C)
{
    constexpr int NKB = 8, N = 512;
    __shared__ f16_t eps[128*136];                 // epilogue only (34.8 KB)
    const int t = threadIdx.x, lane = t & 63, w = t >> 6;
    const int wm = w >> 1, wn = w & 1;             // 2M x 2N waves
    const int quad = lane >> 4, l16 = lane & 15;
    const int id = blockIdx.x;                     // 2048 = 512 x 4
    const int xi = id >> 2, y = id & 3;
    const int r0 = xi * 128, n0 = y * 128;
    const int rt0 = (r0 >> 4) + wm*4;
    const int nt0 = (n0 >> 4) + wn*4;

    f32x4 acc[4][4];
#pragma unroll
    for (int mi = 0; mi < 4; ++mi)
#pragma unroll
        for (int ni = 0; ni < 4; ++ni) acc[mi][ni] = (f32x4){0.f,0.f,0.f,0.f};

    const f16_t* ap = A  + (size_t)rt0 * NKB * 512 + lane*8;
    const f16_t* bp = Wp + (size_t)nt0 * NKB * 512 + lane*8;

#pragma unroll
    for (int kb = 0; kb < NKB; ++kb) {
        half8 a[4], b[4];
#pragma unroll
        for (int mi = 0; mi < 4; ++mi)
            a[mi] = *(const half8*)(ap + ((size_t)mi*NKB + kb)*512);
#pragma unroll
        for (int ni = 0; ni < 4; ++ni)
            b[ni] = *(const half8*)(bp + ((size_t)ni*NKB + kb)*512);
#pragma unroll
        for (int mi = 0; mi < 4; ++mi)
#pragma unroll
            for (int ni = 0; ni < 4; ++ni)
                acc[mi][ni] = __builtin_amdgcn_mfma_f32_16x16x32_f16(
                    a[mi], b[ni], acc[mi][ni], 0, 0, 0);
    }

    // epilogue: all 4 waves write disjoint quadrants, one sync, coalesced stores
#pragma unroll
    for (int ni = 0; ni < 4; ++ni) {
        const int lcol = wn*64 + ni*16 + l16;
        const int col = n0 + lcol;
        const float scale = bng[col] * rsqrtf(bnv[col] + 1e-3f);
        const float shift = bnb[col] - bnm[col] * scale;
        const float bv = bias[col];
#pragma unroll
        for (int mi = 0; mi < 4; ++mi) {
            const int rowb = wm*64 + mi*16 + quad*4;
#pragma unroll
            for (int rr = 0; rr < 4; ++rr) {
                float v = acc[mi][ni][rr] + bv;
                v = fmaxf(v, 0.f);
                v = fmaf(v, scale, shift);
                eps[(rowb + rr)*136 + lcol] = (f16_t)v;
            }
        }
    }
    __syncthreads();
#pragma unroll
    for (int k2 = 0; k2 < 8; ++k2) {
        int idx = k2*256 + t;                       // 2048 uint4 = 128 rows x 16 chunks
        int row = idx >> 4, ch = idx & 15;
        *(uint4*)(C + (size_t)(r0 + row)*N + n0 + ch*8) =
            *(const uint4*)&eps[row*136 + ch*8];
    }
}

// ---------------- segment sum/max over H3[65536x512] -> fp = tanh([ssum|smax]) ----------------
__global__ __launch_bounds__(256)
void reduce_k(const f16_t* __restrict__ H3, const int* __restrict__ slots,
              float* __restrict__ fp) {
    __shared__ float shs[3][512];
    __shared__ float shm[3][512];
    int s = blockIdx.x;
    int t = threadIdx.x;
    int w = t >> 6, l = t & 63;
    int c = l * 8;
    const int* sl = slots + s*32 + w*8;
    float sm[8], mx[8];
#pragma unroll
    for (int e = 0; e < 8; ++e) { sm[e] = 0.f; mx[e] = -INFINITY; }
#pragma unroll
    for (int i = 0; i < 8; ++i) {
        int a = sl[i];
        uint4 raw = *(const uint4*)(H3 + (size_t)a*512 + c);
        const f16_t* u = (const f16_t*)&raw;
#pragma unroll
        for (int e = 0; e < 8; ++e) {
            float f = (float)u[e];
            sm[e] += f;
            mx[e] = fmaxf(mx[e], f);
        }
    }
    if (w) {
        *(float4*)&shs[w-1][c]   = *(float4*)&sm[0];
        *(float4*)&shs[w-1][c+4] = *(float4*)&sm[4];
        *(float4*)&shm[w-1][c]   = *(float4*)&mx[0];
        *(float4*)&shm[w-1][c+4] = *(float4*)&mx[4];
    }
    __syncthreads();
    if (w == 0) {
#pragma unroll
        for (int j = 0; j < 3; ++j)
#pragma unroll
            for (int e = 0; e < 8; ++e) {
                sm[e] += shs[j][c+e];
                mx[e] = fmaxf(mx[e], shm[j][c+e]);
            }
        float o1[8], o2[8];
#pragma unroll
        for (int e = 0; e < 8; ++e) {
            o1[e] = tanhf(sm[e]); o2[e] = tanhf(mx[e]);
        }
        float* fr = fp + (size_t)s*1024;
        *(float4*)(fr + c)       = *(float4*)&o1[0];
        *(float4*)(fr + c + 4)   = *(float4*)&o1[4];
        *(float4*)(fr + 512 + c)     = *(float4*)&o2[0];
        *(float4*)(fr + 512 + c + 4) = *(float4*)&o2[4];
    }
}

// ---------------- readout GEMM: logits = fp @ out_w + out_b; probs = pair-softmax ----------------
__global__ __launch_bounds__(64)
void final_mfma(const float* __restrict__ fp, const f16_t* __restrict__ Wop,
                const float* __restrict__ out_b,
                float* __restrict__ probs, float* __restrict__ logits) {
    const int t = threadIdx.x;
    const int lane = t & 63;
    const int quad = lane >> 4, l16 = lane & 15;
    const int r0 = blockIdx.x * 16;

    f32x4 acc[2];
#pragma unroll
    for (int ni = 0; ni < 2; ++ni) acc[ni] = (f32x4){0.f,0.f,0.f,0.f};

    const size_t rowoff = (size_t)(r0 + l16) * 1024 + quad*8;
    size_t boff[2];
#pragma unroll
    for (int ni = 0; ni < 2; ++ni)
        boff[ni] = (size_t)ni * 32 * 512 + lane*8;

    auto loadA = [&](half8& a, int kb) {
        const float* src = fp + rowoff + kb*32;
        float4 u0 = *(const float4*)(src);
        float4 u1 = *(const float4*)(src + 4);
        half8 h;
        h[0] = (f16_t)u0.x; h[1] = (f16_t)u0.y; h[2] = (f16_t)u0.z; h[3] = (f16_t)u0.w;
        h[4] = (f16_t)u1.x; h[5] = (f16_t)u1.y; h[6] = (f16_t)u1.z; h[7] = (f16_t)u1.w;
        a = h;
    };
    auto loadB = [&](half8* b, int kb) {
#pragma unroll
        for (int ni = 0; ni < 2; ++ni) b[ni] = *(const half8*)(Wop + boff[ni] + (size_t)kb*512);
    };
    auto domfma = [&](half8& a, half8* b) {
#pragma unroll
        for (int ni = 0; ni < 2; ++ni)
            acc[ni] = __builtin_amdgcn_mfma_f32_16x16x32_f16(a, b[ni], acc[ni], 0, 0, 0);
    };

    half8 a0, b0[2], a1, b1[2];
    loadA(a0, 0); loadB(b0, 0);
#pragma unroll
    for (int kb = 0; kb < 32; kb += 2) {
        loadA(a1, kb + 1); loadB(b1, kb + 1);
        domfma(a0, b0);
        if (kb + 2 < 32) { loadA(a0, kb + 2); loadB(b0, kb + 2); }
        domfma(a1, b1);
    }

#pragma unroll
    for (int ni = 0; ni < 2; ++ni) {
        const int c = ni*16 + l16;
        const bool ok = (c < 24);
        const float bv = ok ? out_b[c] : 0.f;
#pragma unroll
        for (int r = 0; r < 4; ++r) {
            float lg = acc[ni][r] + bv;
            float lp = __shfl_xor(lg, 1);
            float m = fmaxf(lg, lp);
            float e  = expf(lg - m);
            float ep = expf(lp - m);
            float pr = e / (e + ep);
            if (ok) {
                int row = r0 + quad*4 + r;
                logits[(size_t)row*24 + c] = lg;
                probs[(size_t)row*24 + c]  = pr;
            }
        }
    }
}

extern "C" void kernel_launch(void* const* d_in, const int* in_sizes, int n_in,
                              void* d_out, int out_size, void* d_ws, size_t ws_size,
                              hipStream_t stream) {
    const float* atom       = (const float*)d_in[0];
    const int*   membership = (const int*)  d_in[2];
    Adj adj;
    for (int d = 0; d < 10; ++d) adj.p[d] = (const int*)d_in[4+d];
    const float* gc1_w0     = (const float*)d_in[14];
    const float* gc1_wself  = (const float*)d_in[15];
    const float* gc1_wneigh = (const float*)d_in[16];
    const float* gc1_b      = (const float*)d_in[17];
    const float* gc2_w0     = (const float*)d_in[18];
    const float* gc2_wself  = (const float*)d_in[19];
    const float* gc2_wneigh = (const float*)d_in[20];
    const float* gc2_b      = (const float*)d_in[21];
    const float* bn1g = (const float*)d_in[22]; const float* bn1b = (const float*)d_in[23];
    const float* bn1m = (const float*)d_in[24]; const float* bn1v = (const float*)d_in[25];
    const float* bn2g = (const float*)d_in[26]; const float* bn2b = (const float*)d_in[27];
    const float* bn2m = (const float*)d_in[28]; const float* bn2v = (const float*)d_in[29];
    const float* bn3g = (const float*)d_in[30]; const float* bn3b = (const float*)d_in[31];
    const float* bn3m = (const float*)d_in[32]; const float* bn3v = (const float*)d_in[33];
    const float* dense_w = (const float*)d_in[34];
    const float* dense_b = (const float*)d_in[35];
    const float* out_w   = (const float*)d_in[36];
    const float* out_b   = (const float*)d_in[37];

    // workspace (f16 units), single copies:
    f16_t* wsb = (f16_t*)d_ws;
    f16_t* xq    = wsb;                        //  6,291,456
    f16_t* NBX   = wsb + 6291456;              //  6,291,456 (blob NKB=3)
    f16_t* H1b   = wsb + 12582912;             // 16,777,216  (also H2; H3 starts here)
    f16_t* P1rm  = wsb + 29360128;             // 16,777,216
    f16_t* NB2b  = wsb + 46137344;             // 16,777,216 (blob NKB=8; later P2_bl)
    f16_t* H2b   = H1b;
    f16_t* P2bl  = NB2b;
    f16_t* H3b   = H1b;                        // 33,554,432 spans H1+P1rm
    f16_t* W1p   = wsb + 62914560;             //    540,672
    f16_t* W2p   = wsb + 63455232;             //  1,441,792
    f16_t* Wdp   = wsb + 64897024;             //    131,072
    f16_t* Wop   = wsb + 65028096;             //     32,768
    int*  counts = (int*)(wsb + 65060864);     // 2048 ints
    int*  slots  = counts + 2048;              // 65536 ints

    float* outp   = (float*)d_out;
    float* probs  = outp;            // 2048*24
    float* logits = outp + 49152;    // 2048*24
    float* fp     = outp + 98304;    // 2048*1024

    pack_cvt<<<11456, 256, 0, stream>>>(gc1_w0, gc1_wself, gc1_wneigh,
                                        gc2_w0, gc2_wself, gc2_wneigh,
                                        dense_w, out_w,
                                        W1p, W2p, Wdp, Wop, counts,
                                        atom, xq);

    // gc1: A0 = xq row-major (kb<3), A1 = NBX blob; 256 panels, NY=1
    nbsum_sc<<<3328, 256, 0, stream>>>(xq, NBX, adj, membership, counts, slots);
    gemm256<6,3,96,3,1,256,true><<<256, 512, 0, stream>>>(
        xq, NBX, W1p, gc1_b, bn1g, bn1b, bn1m, bn1v, H1b);
    pool_k<false><<<(NATOMS*32)/256, 256, 0, stream>>>(H1b, P1rm, adj);

    // gc2: A0 = P1rm row-major (kb<8), A1 = NB2 blob; 256 panels, NY=1
    nbsum_k<<<(NATOMS*32)/256, 256, 0, stream>>>(P1rm, NB2b, adj);
    gemm256<16,8,256,8,1,256,true><<<256, 512, 0, stream>>>(
        P1rm, NB2b, W2p, gc2_b, bn2g, bn2b, bn2m, bn2v, H2b);
    pool_k<true><<<(NATOMS*32)/256, 256, 0, stream>>>(H2b, P2bl, adj);

    // dense: direct blob->reg GEMM, no K-loop barriers; 2048 blocks x 256 thr
    gemm_dir<<<2048, 256, 0, stream>>>(
        P2bl, Wdp, dense_b, bn3g, bn3b, bn3m, bn3v, H3b);

    // segment reduce + tanh -> fp (fp32, in d_out); 4 waves/segment
    reduce_k<<<2048, 256, 0, stream>>>(H3b, slots, fp);

    // readout
    final_mfma<<<128, 64, 0, stream>>>(fp, Wop, out_b, probs, logits);
}

// Round 8
// 346.735 us; speedup vs baseline: 1.0012x; 1.0012x over previous
//
#include <hip/hip_runtime.h>
#include <hip/hip_fp16.h>
#include <math.h>

#define NATOMS 65536

typedef _Float16 f16_t;
typedef __attribute__((ext_vector_type(8))) _Float16 half8;
typedef __attribute__((ext_vector_type(4))) float f32x4;

__constant__ int c_offs[12] = {0,1536,9728,26112,50688,62976,64000,64512,65024,65280,65408,65536};

struct Adj { const int* p[10]; };

__device__ __forceinline__ int seg_of(int row) {
    int s = 0;
#pragma unroll
    for (int i = 1; i <= 10; ++i) s += (row >= c_offs[i]) ? 1 : 0;
    return s;
}

// async global -> LDS, 16 B per lane; LDS dst = wave-uniform base + lane*16
__device__ __forceinline__ void glds16(const f16_t* g, f16_t* l) {
    __builtin_amdgcn_global_load_lds(
        (const __attribute__((address_space(1))) unsigned int*)g,
        (__attribute__((address_space(3))) unsigned int*)l,
        16, 0, 0);
}

// packed f16 max (exact)
__device__ __forceinline__ half8 max8(half8 a, half8 b) {
    half8 r;
#pragma unroll
    for (int e = 0; e < 8; ++e) r[e] = (a[e] >= b[e]) ? a[e] : b[e];
    return r;
}

// Blob layout (MFMA A-fragment order), NKB = cols/32:
//   addr(r,k) = ((r>>4)*NKB + (k>>5))*512 + ((k>>3)&3)*128 + (r&15)*8 + (k&7)
// Key identity: chunk*512 + lane*8 IS the per-lane MFMA fragment -> blob tensors
// can be loaded global->VGPR directly (no LDS round-trip).

// ---------------- merged: weight packing (+ counts zeroing) + cvt_pad ----------------
__global__ void pack_cvt(const float* __restrict__ g1w0, const float* __restrict__ g1ws,
                         const float* __restrict__ g1wn,
                         const float* __restrict__ g2w0, const float* __restrict__ g2ws,
                         const float* __restrict__ g2wn,
                         const float* __restrict__ dw, const float* __restrict__ ow,
                         f16_t* __restrict__ W1p, f16_t* __restrict__ W2p,
                         f16_t* __restrict__ Wdp, f16_t* __restrict__ Wop,
                         int* __restrict__ counts,
                         const float* __restrict__ xf, f16_t* __restrict__ xq) {
    if (blockIdx.x >= 8384) {
        int idx = (blockIdx.x - 8384) * 256 + threadIdx.x;   // 65536*12 exact
        int r = idx / 12;
        int cc = idx - r * 12;
        int c = cc << 3;
        f16_t o[8];
#pragma unroll
        for (int e = 0; e < 8; ++e)
            o[e] = (c + e < 75) ? (f16_t)xf[(size_t)r*75 + c + e] : (f16_t)0.f;
        *(uint4*)(xq + (size_t)r*96 + c) = *(uint4*)o;
        return;
    }
    int idx = blockIdx.x * 256 + threadIdx.x;   // 8384*256 = 2146304 exact
    if (idx < 2048) counts[idx] = 0;
    if (idx < 540672) {
        int j = idx & 7, lane = (idx >> 3) & 63;
        int kb = (idx >> 9) % 6;
        int rest = idx / (512 * 6);
        int ni = rest & 15, s = rest >> 4;
        int k = kb * 32 + (lane >> 4) * 8 + j;
        int n = ni * 16 + (lane & 15);
        float v = 0.f;
        if (k < 75) v = (s == 0) ? g1w0[k*256 + n] : g1ws[((s-1)*75 + k)*256 + n];
        else if (k >= 96 && k < 171 && s > 0) v = g1wn[((s-1)*75 + (k-96))*256 + n];
        W1p[idx] = (f16_t)v;
    } else if (idx < 1982464) {
        int i2 = idx - 540672;
        int j = i2 & 7, lane = (i2 >> 3) & 63;
        int kb = (i2 >> 9) & 15;
        int rest = i2 >> 13;
        int ni = rest & 15, s = rest >> 4;
        int k = kb * 32 + (lane >> 4) * 8 + j;
        int n = ni * 16 + (lane & 15);
        float v = 0.f;
        if (k < 256) v = (s == 0) ? g2w0[k*256 + n] : g2ws[((s-1)*256 + k)*256 + n];
        else if (s > 0) v = g2wn[((s-1)*256 + (k-256))*256 + n];
        W2p[i2] = (f16_t)v;
    } else if (idx < 2113536) {
        int i2 = idx - 1982464;
        int j = i2 & 7, lane = (i2 >> 3) & 63;
        int kb = (i2 >> 9) & 7;
        int ni = (i2 >> 12) & 31;
        int k = kb * 32 + (lane >> 4) * 8 + j;
        int n = ni * 16 + (lane & 15);
        Wdp[i2] = (f16_t)dw[(size_t)k*512 + n];
    } else {
        int i2 = idx - 2113536;
        int j = i2 & 7, lane = (i2 >> 3) & 63;
        int kb = (i2 >> 9) & 31;
        int ni = i2 >> 14;
        int k = kb * 32 + (lane >> 4) * 8 + j;
        int n = ni * 16 + (lane & 15);
        Wop[i2] = (n < 24) ? (f16_t)ow[k*24 + n] : (f16_t)0.f;
    }
}

// ---------------- compile-time-degree gather helpers (row-major sources) ----------------
template<int D, int LD>
__device__ __forceinline__ void gathD(float* v, const f16_t* __restrict__ src,
                                      const int* __restrict__ ap, int c) {
    int rows[D];
#pragma unroll
    for (int j = 0; j < D; ++j) rows[j] = ap[j];
    uint4 raw[D];
#pragma unroll
    for (int j = 0; j < D; ++j) raw[j] = *(const uint4*)(src + (size_t)rows[j]*LD + c);
#pragma unroll
    for (int j = 0; j < D; ++j) {
        const f16_t* u = (const f16_t*)&raw[j];
#pragma unroll
        for (int e = 0; e < 8; ++e) v[e] += (float)u[e];
    }
}

template<int LD>
__device__ __forceinline__ void gath_sum(float* v, const f16_t* __restrict__ src,
                                         const int* __restrict__ ap, int s, int c) {
    switch (s) {
        case 1:  gathD<1,LD>(v,src,ap,c);  break;
        case 2:  gathD<2,LD>(v,src,ap,c);  break;
        case 3:  gathD<3,LD>(v,src,ap,c);  break;
        case 4:  gathD<4,LD>(v,src,ap,c);  break;
        case 5:  gathD<5,LD>(v,src,ap,c);  break;
        case 6:  gathD<6,LD>(v,src,ap,c);  break;
        case 7:  gathD<7,LD>(v,src,ap,c);  break;
        case 8:  gathD<8,LD>(v,src,ap,c);  break;
        case 9:  gathD<9,LD>(v,src,ap,c);  break;
        case 10: gathD<10,LD>(v,src,ap,c); break;
        default: break;
    }
}

template<int D, int LD>
__device__ __forceinline__ void gathD_pk(half8& v, const f16_t* __restrict__ src,
                                         const int* __restrict__ ap, int c) {
    int rows[D];
#pragma unroll
    for (int j = 0; j < D; ++j) rows[j] = ap[j];
    half8 raw[D];
#pragma unroll
    for (int j = 0; j < D; ++j) raw[j] = *(const half8*)(src + (size_t)rows[j]*LD + c);
#pragma unroll
    for (int j = 0; j < D; ++j) v = max8(v, raw[j]);
}

template<int LD>
__device__ __forceinline__ void gath_max(half8& v, const f16_t* __restrict__ src,
                                         const int* __restrict__ ap, int s, int c) {
    switch (s) {
        case 1:  gathD_pk<1,LD>(v,src,ap,c);  break;
        case 2:  gathD_pk<2,LD>(v,src,ap,c);  break;
        case 3:  gathD_pk<3,LD>(v,src,ap,c);  break;
        case 4:  gathD_pk<4,LD>(v,src,ap,c);  break;
        case 5:  gathD_pk<5,LD>(v,src,ap,c);  break;
        case 6:  gathD_pk<6,LD>(v,src,ap,c);  break;
        case 7:  gathD_pk<7,LD>(v,src,ap,c);  break;
        case 8:  gathD_pk<8,LD>(v,src,ap,c);  break;
        case 9:  gathD_pk<9,LD>(v,src,ap,c);  break;
        case 10: gathD_pk<10,LD>(v,src,ap,c); break;
        default: break;
    }
}

// ---------------- merged: NBX = sum_neigh xq (BLOB NKB=3)  +  segment scatter ----------------
__global__ __launch_bounds__(256) void nbsum_sc(const f16_t* __restrict__ xq,
                                                f16_t* __restrict__ NBX, Adj adj,
                                                const int* __restrict__ mem,
                                                int* __restrict__ counts,
                                                int* __restrict__ slots) {
    if (blockIdx.x >= 3072) {
        int i = (blockIdx.x - 3072) * 256 + threadIdx.x;   // 65536 exact
        int s = mem[i];
        int p = atomicAdd(&counts[s], 1);
        if (p < 32) slots[s*32 + p] = i;
        return;
    }
    int idx = blockIdx.x * 256 + threadIdx.x;   // 65536*12 exact, dense
    int r = (int)((unsigned)idx / 12u);
    int cc = idx - r * 12;
    int c = cc << 3;
    int s = seg_of(r);
    float v[8];
#pragma unroll
    for (int e = 0; e < 8; ++e) v[e] = 0.f;
    if (s > 0)
        gath_sum<96>(v, xq, adj.p[s-1] + (size_t)(r - c_offs[s]) * s, s, c);
    f16_t o[8];
#pragma unroll
    for (int e = 0; e < 8; ++e) o[e] = (f16_t)v[e];
    *(uint4*)(NBX + (size_t)(r>>4)*1536 + (c>>5)*512 + ((c>>3)&3)*128 + (r&15)*8) = *(uint4*)o;
}

// ---------------- graph pool: max over self+neighbors; packed f16; output rm or blob ----------------
template<bool BLOB>
__global__ __launch_bounds__(256) void pool_k(const f16_t* __restrict__ H,
                                              f16_t* __restrict__ P, Adj adj) {
    int idx = blockIdx.x * 256 + threadIdx.x;   // 65536*32 exact
    int r = idx >> 5;
    int c = (idx & 31) << 3;
    int s = seg_of(r);
    half8 v = *(const half8*)(H + (size_t)r*256 + c);
    if (s > 0)
        gath_max<256>(v, H, adj.p[s-1] + (size_t)(r - c_offs[s]) * s, s, c);
    if (BLOB)
        *(half8*)(P + (size_t)(r>>4)*4096 + (c>>5)*512 + ((c>>3)&3)*128 + (r&15)*8) = v;
    else
        *(half8*)(P + (size_t)r*256 + c) = v;
}

// ---------------- neighbor-sum of pooled features (reads rm, writes BLOB NKB=8) ----------------
__global__ __launch_bounds__(256) void nbsum_k(const f16_t* __restrict__ P,
                                               f16_t* __restrict__ NB, Adj adj) {
    int idx = blockIdx.x * 256 + threadIdx.x;   // 65536*32 exact
    int r = idx >> 5;
    int c = (idx & 31) << 3;
    int s = seg_of(r);
    float v[8];
#pragma unroll
    for (int e = 0; e < 8; ++e) v[e] = 0.f;
    if (s > 0)
        gath_sum<256>(v, P, adj.p[s-1] + (size_t)(r - c_offs[s]) * s, s, c);
    f16_t o[8];
#pragma unroll
    for (int e = 0; e < 8; ++e) o[e] = (f16_t)v[e];
    *(uint4*)(NB + (size_t)(r>>4)*4096 + (c>>5)*512 + ((c>>3)&3)*128 + (r&15)*8) = *(uint4*)o;
}

// ---------------- 256x256-tile 8-wave f16 MFMA GEMM, BK=32 dbuf (gc1/gc2) ----------------
template<int NKB, int KSPB, int LDA, int NKBA1, int NY, int N, bool SEG>
__global__ __launch_bounds__(512, 2)
void gemm256(const f16_t* __restrict__ A0, const f16_t* __restrict__ A1,
             const f16_t* __restrict__ Wp,
             const float* __restrict__ bias,
             const float* __restrict__ bng, const float* __restrict__ bnb,
             const float* __restrict__ bnm, const float* __restrict__ bnv,
             f16_t* __restrict__ C)
{
    constexpr int NT  = NKB;                  // K-tiles of 32
    constexpr int NNT = N / 16;
    __shared__ f16_t sm[32768];               // 2 x 32 KB

    const int t = threadIdx.x;
    const int lane = t & 63, w = t >> 6;
    const int wm = w >> 2, wn = w & 3;        // 2M x 4N waves
    const int quad = lane >> 4, l16 = lane & 15;
    const int id = blockIdx.x;
    const int xi = id / NY, y = id - xi * NY;
    const int r0 = xi * 256;
    const int n0 = y * 256;
    const int rtg = r0 >> 4;
    const int nbase = n0 >> 4;
    const int segB = SEG ? seg_of(r0) : 0;
    const bool strad = SEG && (seg_of(r0 + 255) != segB);
    const int segw = SEG ? seg_of(r0 + wm*128) : 0;

    f32x4 acc[8][4];
#pragma unroll
    for (int mi = 0; mi < 8; ++mi)
#pragma unroll
        for (int ni = 0; ni < 4; ++ni) acc[mi][ni] = (f32x4){0.f,0.f,0.f,0.f};

    size_t aoff[2];
#pragma unroll
    for (int i = 0; i < 2; ++i)
        aoff[i] = (size_t)(r0 + (w*2 + i)*16 + l16) * LDA + quad*8;

    auto stage = [&](int kb, int buf) {
        f16_t* bb = sm + buf*16384;
#pragma unroll
        for (int i = 0; i < 2; ++i) {
            const int rt = w*2 + i;
            if constexpr (KSPB > 0) {
                if (kb < KSPB)
                    glds16(A0 + (size_t)kb*32 + aoff[i], bb + rt*512);
                else
                    glds16(A1 + ((size_t)(rtg + rt)*NKBA1 + (kb - KSPB))*512 + lane*8,
                           bb + rt*512);
            } else {
                glds16(A1 + ((size_t)(rtg + rt)*NKBA1 + kb)*512 + lane*8,
                       bb + rt*512);
            }
            glds16(Wp + ((size_t)(segB*NNT + nbase + rt)*NKB + kb)*512 + lane*8,
                   bb + 8192 + rt*512);
        }
    };

    stage(0, 0);
    __syncthreads();

    for (int kt = 0; kt < NT; ++kt) {
        const int buf = kt & 1;
        if (kt + 1 < NT) stage(kt + 1, buf ^ 1);    // prefetch overlaps compute
        const f16_t* bb = sm + buf*16384;

        half8 bfr[4];
        if (strad) {
#pragma unroll
            for (int ni = 0; ni < 4; ++ni)
                bfr[ni] = *(const half8*)(Wp +
                    ((size_t)(segw*NNT + nbase + wn*4 + ni)*NKB + kt)*512 + lane*8);
        } else {
#pragma unroll
            for (int ni = 0; ni < 4; ++ni)
                bfr[ni] = *(const half8*)(bb + 8192 + (wn*4 + ni)*512 + lane*8);
        }

#pragma unroll
        for (int ph = 0; ph < 4; ++ph) {
            half8 a[2];
#pragma unroll
            for (int m2 = 0; m2 < 2; ++m2)
                a[m2] = *(const half8*)(bb + (wm*8 + ph*2 + m2)*512 + lane*8);
#pragma unroll
            for (int m2 = 0; m2 < 2; ++m2)
#pragma unroll
                for (int ni = 0; ni < 4; ++ni)
                    acc[ph*2 + m2][ni] = __builtin_amdgcn_mfma_f32_16x16x32_f16(
                        a[m2], bfr[ni], acc[ph*2 + m2][ni], 0, 0, 0);
        }
        __syncthreads();
    }

    // epilogue: 4 strips of 64 rows via LDS, coalesced 16-B stores
    f16_t* eps = sm;
#pragma unroll
    for (int s = 0; s < 4; ++s) {
        if (wm == (s >> 1)) {
#pragma unroll
            for (int ni = 0; ni < 4; ++ni) {
                const int lcol = wn*64 + ni*16 + l16;
                const int col = n0 + lcol;
                const float scale = bng[col] * rsqrtf(bnv[col] + 1e-3f);
                const float shift = bnb[col] - bnm[col] * scale;
                const float bv = bias[(SEG ? segw*N : 0) + col];
#pragma unroll
                for (int m2 = 0; m2 < 4; ++m2) {
                    const int mi = (s & 1)*4 + m2;
                    const int rowb = m2*16 + quad*4;
#pragma unroll
                    for (int rr = 0; rr < 4; ++rr) {
                        float v = acc[mi][ni][rr] + bv;
                        v = fmaxf(v, 0.f);
                        v = fmaf(v, scale, shift);
                        eps[(rowb + rr)*264 + lcol] = (f16_t)v;
                    }
                }
            }
        }
        __syncthreads();
#pragma unroll
        for (int k = 0; k < 4; ++k) {
            int idx = k*512 + t;                    // 2048 uint4 = 64 rows x 32 chunks
            int row = idx >> 5, ch = idx & 31;
            *(uint4*)(C + (size_t)(r0 + s*64 + row)*N + n0 + ch*8) =
                *(const uint4*)&eps[row*264 + ch*8];
        }
        __syncthreads();
    }
}

// ---------------- dense GEMM: direct blob->register, ZERO K-loop LDS/barriers ----------------
// R7: XCD-grouped block mapping (T1). All 4 y-blocks of an xi-panel land on the SAME
// XCD (round-robin id%8 = XCD) and run back-to-back -> A panel fetched beyond-L2 once.
// ~16 live panels x 4 y per XCD = ~1 MB A + 0.26 MB B, L2-resident.
__global__ __launch_bounds__(256, 4)
void gemm_dir(const f16_t* __restrict__ A, const f16_t* __restrict__ Wp,
              const float* __restrict__ bias,
              const float* __restrict__ bng, const float* __restrict__ bnb,
              const float* __restrict__ bnm, const float* __restrict__ bnv,
              f16_t* __restrict__ C)
{
    constexpr int NKB = 8, N = 512;
    __shared__ f16_t eps[128*136];                 // epilogue only (34.8 KB)
    const int t = threadIdx.x, lane = t & 63, w = t >> 6;
    const int wm = w >> 1, wn = w & 1;             // 2M x 2N waves
    const int quad = lane >> 4, l16 = lane & 15;
    const int id = blockIdx.x;                     // 2048 = 8 xcd x 64 xi x 4 y
    const int xcd = id & 7;
    const int j = id >> 3;
    const int xi = xcd * 64 + (j >> 2);
    const int y = j & 3;
    const int r0 = xi * 128, n0 = y * 128;
    const int rt0 = (r0 >> 4) + wm*4;
    const int nt0 = (n0 >> 4) + wn*4;

    f32x4 acc[4][4];
#pragma unroll
    for (int mi = 0; mi < 4; ++mi)
#pragma unroll
        for (int ni = 0; ni < 4; ++ni) acc[mi][ni] = (f32x4){0.f,0.f,0.f,0.f};

    const f16_t* ap = A  + (size_t)rt0 * NKB * 512 + lane*8;
    const f16_t* bp = Wp + (size_t)nt0 * NKB * 512 + lane*8;

#pragma unroll
    for (int kb = 0; kb < NKB; ++kb) {
        half8 a[4], b[4];
#pragma unroll
        for (int mi = 0; mi < 4; ++mi)
            a[mi] = *(const half8*)(ap + ((size_t)mi*NKB + kb)*512);
#pragma unroll
        for (int ni = 0; ni < 4; ++ni)
            b[ni] = *(const half8*)(bp + ((size_t)ni*NKB + kb)*512);
#pragma unroll
        for (int mi = 0; mi < 4; ++mi)
#pragma unroll
            for (int ni = 0; ni < 4; ++ni)
                acc[mi][ni] = __builtin_amdgcn_mfma_f32_16x16x32_f16(
                    a[mi], b[ni], acc[mi][ni], 0, 0, 0);
    }

    // epilogue: all 4 waves write disjoint quadrants, one sync, coalesced stores
#pragma unroll
    for (int ni = 0; ni < 4; ++ni) {
        const int lcol = wn*64 + ni*16 + l16;
        const int col = n0 + lcol;
        const float scale = bng[col] * rsqrtf(bnv[col] + 1e-3f);
        const float shift = bnb[col] - bnm[col] * scale;
        const float bv = bias[col];
#pragma unroll
        for (int mi = 0; mi < 4; ++mi) {
            const int rowb = wm*64 + mi*16 + quad*4;
#pragma unroll
            for (int rr = 0; rr < 4; ++rr) {
                float v = acc[mi][ni][rr] + bv;
                v = fmaxf(v, 0.f);
                v = fmaf(v, scale, shift);
                eps[(rowb + rr)*136 + lcol] = (f16_t)v;
            }
        }
    }
    __syncthreads();
#pragma unroll
    for (int k2 = 0; k2 < 8; ++k2) {
        int idx = k2*256 + t;                       // 2048 uint4 = 128 rows x 16 chunks
        int row = idx >> 4, ch = idx & 15;
        *(uint4*)(C + (size_t)(r0 + row)*N + n0 + ch*8) =
            *(const uint4*)&eps[row*136 + ch*8];
    }
}

// ---------------- segment sum/max over H3[65536x512] -> fp = tanh([ssum|smax]) ----------------
__global__ __launch_bounds__(256)
void reduce_k(const f16_t* __restrict__ H3, const int* __restrict__ slots,
              float* __restrict__ fp) {
    __shared__ float shs[3][512];
    __shared__ float shm[3][512];
    int s = blockIdx.x;
    int t = threadIdx.x;
    int w = t >> 6, l = t & 63;
    int c = l * 8;
    const int* sl = slots + s*32 + w*8;
    float sm[8], mx[8];
#pragma unroll
    for (int e = 0; e < 8; ++e) { sm[e] = 0.f; mx[e] = -INFINITY; }
#pragma unroll
    for (int i = 0; i < 8; ++i) {
        int a = sl[i];
        uint4 raw = *(const uint4*)(H3 + (size_t)a*512 + c);
        const f16_t* u = (const f16_t*)&raw;
#pragma unroll
        for (int e = 0; e < 8; ++e) {
            float f = (float)u[e];
            sm[e] += f;
            mx[e] = fmaxf(mx[e], f);
        }
    }
    if (w) {
        *(float4*)&shs[w-1][c]   = *(float4*)&sm[0];
        *(float4*)&shs[w-1][c+4] = *(float4*)&sm[4];
        *(float4*)&shm[w-1][c]   = *(float4*)&mx[0];
        *(float4*)&shm[w-1][c+4] = *(float4*)&mx[4];
    }
    __syncthreads();
    if (w == 0) {
#pragma unroll
        for (int j = 0; j < 3; ++j)
#pragma unroll
            for (int e = 0; e < 8; ++e) {
                sm[e] += shs[j][c+e];
                mx[e] = fmaxf(mx[e], shm[j][c+e]);
            }
        float o1[8], o2[8];
#pragma unroll
        for (int e = 0; e < 8; ++e) {
            o1[e] = tanhf(sm[e]); o2[e] = tanhf(mx[e]);
        }
        float* fr = fp + (size_t)s*1024;
        *(float4*)(fr + c)       = *(float4*)&o1[0];
        *(float4*)(fr + c + 4)   = *(float4*)&o1[4];
        *(float4*)(fr + 512 + c)     = *(float4*)&o2[0];
        *(float4*)(fr + 512 + c + 4) = *(float4*)&o2[4];
    }
}

// ---------------- readout GEMM: logits = fp @ out_w + out_b; probs = pair-softmax ----------------
__global__ __launch_bounds__(64)
void final_mfma(const float* __restrict__ fp, const f16_t* __restrict__ Wop,
                const float* __restrict__ out_b,
                float* __restrict__ probs, float* __restrict__ logits) {
    const int t = threadIdx.x;
    const int lane = t & 63;
    const int quad = lane >> 4, l16 = lane & 15;
    const int r0 = blockIdx.x * 16;

    f32x4 acc[2];
#pragma unroll
    for (int ni = 0; ni < 2; ++ni) acc[ni] = (f32x4){0.f,0.f,0.f,0.f};

    const size_t rowoff = (size_t)(r0 + l16) * 1024 + quad*8;
    size_t boff[2];
#pragma unroll
    for (int ni = 0; ni < 2; ++ni)
        boff[ni] = (size_t)ni * 32 * 512 + lane*8;

    auto loadA = [&](half8& a, int kb) {
        const float* src = fp + rowoff + kb*32;
        float4 u0 = *(const float4*)(src);
        float4 u1 = *(const float4*)(src + 4);
        half8 h;
        h[0] = (f16_t)u0.x; h[1] = (f16_t)u0.y; h[2] = (f16_t)u0.z; h[3] = (f16_t)u0.w;
        h[4] = (f16_t)u1.x; h[5] = (f16_t)u1.y; h[6] = (f16_t)u1.z; h[7] = (f16_t)u1.w;
        a = h;
    };
    auto loadB = [&](half8* b, int kb) {
#pragma unroll
        for (int ni = 0; ni < 2; ++ni) b[ni] = *(const half8*)(Wop + boff[ni] + (size_t)kb*512);
    };
    auto domfma = [&](half8& a, half8* b) {
#pragma unroll
        for (int ni = 0; ni < 2; ++ni)
            acc[ni] = __builtin_amdgcn_mfma_f32_16x16x32_f16(a, b[ni], acc[ni], 0, 0, 0);
    };

    half8 a0, b0[2], a1, b1[2];
    loadA(a0, 0); loadB(b0, 0);
#pragma unroll
    for (int kb = 0; kb < 32; kb += 2) {
        loadA(a1, kb + 1); loadB(b1, kb + 1);
        domfma(a0, b0);
        if (kb + 2 < 32) { loadA(a0, kb + 2); loadB(b0, kb + 2); }
        domfma(a1, b1);
    }

#pragma unroll
    for (int ni = 0; ni < 2; ++ni) {
        const int c = ni*16 + l16;
        const bool ok = (c < 24);
        const float bv = ok ? out_b[c] : 0.f;
#pragma unroll
        for (int r = 0; r < 4; ++r) {
            float lg = acc[ni][r] + bv;
            float lp = __shfl_xor(lg, 1);
            float m = fmaxf(lg, lp);
            float e  = expf(lg - m);
            float ep = expf(lp - m);
            float pr = e / (e + ep);
            if (ok) {
                int row = r0 + quad*4 + r;
                logits[(size_t)row*24 + c] = lg;
                probs[(size_t)row*24 + c]  = pr;
            }
        }
    }
}

extern "C" void kernel_launch(void* const* d_in, const int* in_sizes, int n_in,
                              void* d_out, int out_size, void* d_ws, size_t ws_size,
                              hipStream_t stream) {
    const float* atom       = (const float*)d_in[0];
    const int*   membership = (const int*)  d_in[2];
    Adj adj;
    for (int d = 0; d < 10; ++d) adj.p[d] = (const int*)d_in[4+d];
    const float* gc1_w0     = (const float*)d_in[14];
    const float* gc1_wself  = (const float*)d_in[15];
    const float* gc1_wneigh = (const float*)d_in[16];
    const float* gc1_b      = (const float*)d_in[17];
    const float* gc2_w0     = (const float*)d_in[18];
    const float* gc2_wself  = (const float*)d_in[19];
    const float* gc2_wneigh = (const float*)d_in[20];
    const float* gc2_b      = (const float*)d_in[21];
    const float* bn1g = (const float*)d_in[22]; const float* bn1b = (const float*)d_in[23];
    const float* bn1m = (const float*)d_in[24]; const float* bn1v = (const float*)d_in[25];
    const float* bn2g = (const float*)d_in[26]; const float* bn2b = (const float*)d_in[27];
    const float* bn2m = (const float*)d_in[28]; const float* bn2v = (const float*)d_in[29];
    const float* bn3g = (const float*)d_in[30]; const float* bn3b = (const float*)d_in[31];
    const float* bn3m = (const float*)d_in[32]; const float* bn3v = (const float*)d_in[33];
    const float* dense_w = (const float*)d_in[34];
    const float* dense_b = (const float*)d_in[35];
    const float* out_w   = (const float*)d_in[36];
    const float* out_b   = (const float*)d_in[37];

    // workspace (f16 units), single copies:
    f16_t* wsb = (f16_t*)d_ws;
    f16_t* xq    = wsb;                        //  6,291,456
    f16_t* NBX   = wsb + 6291456;              //  6,291,456 (blob NKB=3)
    f16_t* H1b   = wsb + 12582912;             // 16,777,216  (also H2; H3 starts here)
    f16_t* P1rm  = wsb + 29360128;             // 16,777,216
    f16_t* NB2b  = wsb + 46137344;             // 16,777,216 (blob NKB=8; later P2_bl)
    f16_t* H2b   = H1b;
    f16_t* P2bl  = NB2b;
    f16_t* H3b   = H1b;                        // 33,554,432 spans H1+P1rm
    f16_t* W1p   = wsb + 62914560;             //    540,672
    f16_t* W2p   = wsb + 63455232;             //  1,441,792
    f16_t* Wdp   = wsb + 64897024;             //    131,072
    f16_t* Wop   = wsb + 65028096;             //     32,768
    int*  counts = (int*)(wsb + 65060864);     // 2048 ints
    int*  slots  = counts + 2048;              // 65536 ints

    float* outp   = (float*)d_out;
    float* probs  = outp;            // 2048*24
    float* logits = outp + 49152;    // 2048*24
    float* fp     = outp + 98304;    // 2048*1024

    pack_cvt<<<11456, 256, 0, stream>>>(gc1_w0, gc1_wself, gc1_wneigh,
                                        gc2_w0, gc2_wself, gc2_wneigh,
                                        dense_w, out_w,
                                        W1p, W2p, Wdp, Wop, counts,
                                        atom, xq);

    // gc1: A0 = xq row-major (kb<3), A1 = NBX blob; 256 panels, NY=1
    nbsum_sc<<<3328, 256, 0, stream>>>(xq, NBX, adj, membership, counts, slots);
    gemm256<6,3,96,3,1,256,true><<<256, 512, 0, stream>>>(
        xq, NBX, W1p, gc1_b, bn1g, bn1b, bn1m, bn1v, H1b);
    pool_k<false><<<(NATOMS*32)/256, 256, 0, stream>>>(H1b, P1rm, adj);

    // gc2: A0 = P1rm row-major (kb<8), A1 = NB2 blob; 256 panels, NY=1
    nbsum_k<<<(NATOMS*32)/256, 256, 0, stream>>>(P1rm, NB2b, adj);
    gemm256<16,8,256,8,1,256,true><<<256, 512, 0, stream>>>(
        P1rm, NB2b, W2p, gc2_b, bn2g, bn2b, bn2m, bn2v, H2b);
    pool_k<true><<<(NATOMS*32)/256, 256, 0, stream>>>(H2b, P2bl, adj);

    // dense: direct blob->reg GEMM, XCD-grouped mapping; 2048 blocks x 256 thr
    gemm_dir<<<2048, 256, 0, stream>>>(
        P2bl, Wdp, dense_b, bn3g, bn3b, bn3m, bn3v, H3b);

    // segment reduce + tanh -> fp (fp32, in d_out); 4 waves/segment
    reduce_k<<<2048, 256, 0, stream>>>(H3b, slots, fp);

    // readout
    final_mfma<<<128, 64, 0, stream>>>(fp, Wop, out_b, probs, logits);
}

// Round 10
// 338.505 us; speedup vs baseline: 1.0255x; 1.0243x over previous
//
#include <hip/hip_runtime.h>
#include <hip/hip_fp16.h>
#include <math.h>

#define NATOMS 65536

typedef _Float16 f16_t;
typedef __attribute__((ext_vector_type(8))) _Float16 half8;
typedef __attribute__((ext_vector_type(4))) float f32x4;

__constant__ int c_offs[12] = {0,1536,9728,26112,50688,62976,64000,64512,65024,65280,65408,65536};

struct Adj { const int* p[10]; };

__device__ __forceinline__ int seg_of(int row) {
    int s = 0;
#pragma unroll
    for (int i = 1; i <= 10; ++i) s += (row >= c_offs[i]) ? 1 : 0;
    return s;
}

// async global -> LDS, 16 B per lane; LDS dst = wave-uniform base + lane*16
__device__ __forceinline__ void glds16(const f16_t* g, f16_t* l) {
    __builtin_amdgcn_global_load_lds(
        (const __attribute__((address_space(1))) unsigned int*)g,
        (__attribute__((address_space(3))) unsigned int*)l,
        16, 0, 0);
}

// packed f16 max (exact)
__device__ __forceinline__ half8 max8(half8 a, half8 b) {
    half8 r;
#pragma unroll
    for (int e = 0; e < 8; ++e) r[e] = (a[e] >= b[e]) ? a[e] : b[e];
    return r;
}

// Blob layout (MFMA A-fragment order), NKB = cols/32:
//   addr(r,k) = ((r>>4)*NKB + (k>>5))*512 + ((k>>3)&3)*128 + (r&15)*8 + (k&7)
// Key identity: chunk*512 + lane*8 IS the per-lane MFMA fragment -> blob tensors
// can be loaded global->VGPR directly (no LDS round-trip).

// ---------------- merged: weight packing (+ counts zeroing) + cvt_pad ----------------
__global__ void pack_cvt(const float* __restrict__ g1w0, const float* __restrict__ g1ws,
                         const float* __restrict__ g1wn,
                         const float* __restrict__ g2w0, const float* __restrict__ g2ws,
                         const float* __restrict__ g2wn,
                         const float* __restrict__ dw, const float* __restrict__ ow,
                         f16_t* __restrict__ W1p, f16_t* __restrict__ W2p,
                         f16_t* __restrict__ Wdp, f16_t* __restrict__ Wop,
                         int* __restrict__ counts,
                         const float* __restrict__ xf, f16_t* __restrict__ xq) {
    if (blockIdx.x >= 8384) {
        int idx = (blockIdx.x - 8384) * 256 + threadIdx.x;   // 65536*12 exact
        int r = idx / 12;
        int cc = idx - r * 12;
        int c = cc << 3;
        f16_t o[8];
#pragma unroll
        for (int e = 0; e < 8; ++e)
            o[e] = (c + e < 75) ? (f16_t)xf[(size_t)r*75 + c + e] : (f16_t)0.f;
        *(uint4*)(xq + (size_t)r*96 + c) = *(uint4*)o;
        return;
    }
    int idx = blockIdx.x * 256 + threadIdx.x;   // 8384*256 = 2146304 exact
    if (idx < 2048) counts[idx] = 0;
    if (idx < 540672) {
        int j = idx & 7, lane = (idx >> 3) & 63;
        int kb = (idx >> 9) % 6;
        int rest = idx / (512 * 6);
        int ni = rest & 15, s = rest >> 4;
        int k = kb * 32 + (lane >> 4) * 8 + j;
        int n = ni * 16 + (lane & 15);
        float v = 0.f;
        if (k < 75) v = (s == 0) ? g1w0[k*256 + n] : g1ws[((s-1)*75 + k)*256 + n];
        else if (k >= 96 && k < 171 && s > 0) v = g1wn[((s-1)*75 + (k-96))*256 + n];
        W1p[idx] = (f16_t)v;
    } else if (idx < 1982464) {
        int i2 = idx - 540672;
        int j = i2 & 7, lane = (i2 >> 3) & 63;
        int kb = (i2 >> 9) & 15;
        int rest = i2 >> 13;
        int ni = rest & 15, s = rest >> 4;
        int k = kb * 32 + (lane >> 4) * 8 + j;
        int n = ni * 16 + (lane & 15);
        float v = 0.f;
        if (k < 256) v = (s == 0) ? g2w0[k*256 + n] : g2ws[((s-1)*256 + k)*256 + n];
        else if (s > 0) v = g2wn[((s-1)*256 + (k-256))*256 + n];
        W2p[i2] = (f16_t)v;
    } else if (idx < 2113536) {
        int i2 = idx - 1982464;
        int j = i2 & 7, lane = (i2 >> 3) & 63;
        int kb = (i2 >> 9) & 7;
        int ni = (i2 >> 12) & 31;
        int k = kb * 32 + (lane >> 4) * 8 + j;
        int n = ni * 16 + (lane & 15);
        Wdp[i2] = (f16_t)dw[(size_t)k*512 + n];
    } else {
        int i2 = idx - 2113536;
        int j = i2 & 7, lane = (i2 >> 3) & 63;
        int kb = (i2 >> 9) & 31;
        int ni = i2 >> 14;
        int k = kb * 32 + (lane >> 4) * 8 + j;
        int n = ni * 16 + (lane & 15);
        Wop[i2] = (n < 24) ? (f16_t)ow[k*24 + n] : (f16_t)0.f;
    }
}

// ---------------- compile-time-degree gather helpers (row-major sources) ----------------
template<int D, int LD>
__device__ __forceinline__ void gathD(float* v, const f16_t* __restrict__ src,
                                      const int* __restrict__ ap, int c) {
    int rows[D];
#pragma unroll
    for (int j = 0; j < D; ++j) rows[j] = ap[j];
    uint4 raw[D];
#pragma unroll
    for (int j = 0; j < D; ++j) raw[j] = *(const uint4*)(src + (size_t)rows[j]*LD + c);
#pragma unroll
    for (int j = 0; j < D; ++j) {
        const f16_t* u = (const f16_t*)&raw[j];
#pragma unroll
        for (int e = 0; e < 8; ++e) v[e] += (float)u[e];
    }
}

template<int LD>
__device__ __forceinline__ void gath_sum(float* v, const f16_t* __restrict__ src,
                                         const int* __restrict__ ap, int s, int c) {
    switch (s) {
        case 1:  gathD<1,LD>(v,src,ap,c);  break;
        case 2:  gathD<2,LD>(v,src,ap,c);  break;
        case 3:  gathD<3,LD>(v,src,ap,c);  break;
        case 4:  gathD<4,LD>(v,src,ap,c);  break;
        case 5:  gathD<5,LD>(v,src,ap,c);  break;
        case 6:  gathD<6,LD>(v,src,ap,c);  break;
        case 7:  gathD<7,LD>(v,src,ap,c);  break;
        case 8:  gathD<8,LD>(v,src,ap,c);  break;
        case 9:  gathD<9,LD>(v,src,ap,c);  break;
        case 10: gathD<10,LD>(v,src,ap,c); break;
        default: break;
    }
}

template<int D, int LD>
__device__ __forceinline__ void gathD_pk(half8& v, const f16_t* __restrict__ src,
                                         const int* __restrict__ ap, int c) {
    int rows[D];
#pragma unroll
    for (int j = 0; j < D; ++j) rows[j] = ap[j];
    half8 raw[D];
#pragma unroll
    for (int j = 0; j < D; ++j) raw[j] = *(const half8*)(src + (size_t)rows[j]*LD + c);
#pragma unroll
    for (int j = 0; j < D; ++j) v = max8(v, raw[j]);
}

template<int LD>
__device__ __forceinline__ void gath_max(half8& v, const f16_t* __restrict__ src,
                                         const int* __restrict__ ap, int s, int c) {
    switch (s) {
        case 1:  gathD_pk<1,LD>(v,src,ap,c);  break;
        case 2:  gathD_pk<2,LD>(v,src,ap,c);  break;
        case 3:  gathD_pk<3,LD>(v,src,ap,c);  break;
        case 4:  gathD_pk<4,LD>(v,src,ap,c);  break;
        case 5:  gathD_pk<5,LD>(v,src,ap,c);  break;
        case 6:  gathD_pk<6,LD>(v,src,ap,c);  break;
        case 7:  gathD_pk<7,LD>(v,src,ap,c);  break;
        case 8:  gathD_pk<8,LD>(v,src,ap,c);  break;
        case 9:  gathD_pk<9,LD>(v,src,ap,c);  break;
        case 10: gathD_pk<10,LD>(v,src,ap,c); break;
        default: break;
    }
}

// ---------------- merged: NBX = sum_neigh xq (BLOB NKB=3)  +  segment scatter ----------------
__global__ __launch_bounds__(256) void nbsum_sc(const f16_t* __restrict__ xq,
                                                f16_t* __restrict__ NBX, Adj adj,
                                                const int* __restrict__ mem,
                                                int* __restrict__ counts,
                                                int* __restrict__ slots) {
    if (blockIdx.x >= 3072) {
        int i = (blockIdx.x - 3072) * 256 + threadIdx.x;   // 65536 exact
        int s = mem[i];
        int p = atomicAdd(&counts[s], 1);
        if (p < 32) slots[s*32 + p] = i;
        return;
    }
    int idx = blockIdx.x * 256 + threadIdx.x;   // 65536*12 exact, dense
    int r = (int)((unsigned)idx / 12u);
    int cc = idx - r * 12;
    int c = cc << 3;
    int s = seg_of(r);
    float v[8];
#pragma unroll
    for (int e = 0; e < 8; ++e) v[e] = 0.f;
    if (s > 0)
        gath_sum<96>(v, xq, adj.p[s-1] + (size_t)(r - c_offs[s]) * s, s, c);
    f16_t o[8];
#pragma unroll
    for (int e = 0; e < 8; ++e) o[e] = (f16_t)v[e];
    *(uint4*)(NBX + (size_t)(r>>4)*1536 + (c>>5)*512 + ((c>>3)&3)*128 + (r&15)*8) = *(uint4*)o;
}

// ---------------- graph pool: max over self+neighbors; packed f16; output rm or blob ----------------
template<bool BLOB>
__global__ __launch_bounds__(256) void pool_k(const f16_t* __restrict__ H,
                                              f16_t* __restrict__ P, Adj adj) {
    int idx = blockIdx.x * 256 + threadIdx.x;   // 65536*32 exact
    int r = idx >> 5;
    int c = (idx & 31) << 3;
    int s = seg_of(r);
    half8 v = *(const half8*)(H + (size_t)r*256 + c);
    if (s > 0)
        gath_max<256>(v, H, adj.p[s-1] + (size_t)(r - c_offs[s]) * s, s, c);
    if (BLOB)
        *(half8*)(P + (size_t)(r>>4)*4096 + (c>>5)*512 + ((c>>3)&3)*128 + (r&15)*8) = v;
    else
        *(half8*)(P + (size_t)r*256 + c) = v;
}

// ---------------- neighbor-sum of pooled features (reads rm, writes BLOB NKB=8) ----------------
__global__ __launch_bounds__(256) void nbsum_k(const f16_t* __restrict__ P,
                                               f16_t* __restrict__ NB, Adj adj) {
    int idx = blockIdx.x * 256 + threadIdx.x;   // 65536*32 exact
    int r = idx >> 5;
    int c = (idx & 31) << 3;
    int s = seg_of(r);
    float v[8];
#pragma unroll
    for (int e = 0; e < 8; ++e) v[e] = 0.f;
    if (s > 0)
        gath_sum<256>(v, P, adj.p[s-1] + (size_t)(r - c_offs[s]) * s, s, c);
    f16_t o[8];
#pragma unroll
    for (int e = 0; e < 8; ++e) o[e] = (f16_t)v[e];
    *(uint4*)(NB + (size_t)(r>>4)*4096 + (c>>5)*512 + ((c>>3)&3)*128 + (r&15)*8) = *(uint4*)o;
}

// ---------------- 256x256-tile 8-wave f16 MFMA GEMM, BK=32 dbuf (gc1/gc2) ----------------
template<int NKB, int KSPB, int LDA, int NKBA1, int NY, int N, bool SEG>
__global__ __launch_bounds__(512, 2)
void gemm256(const f16_t* __restrict__ A0, const f16_t* __restrict__ A1,
             const f16_t* __restrict__ Wp,
             const float* __restrict__ bias,
             const float* __restrict__ bng, const float* __restrict__ bnb,
             const float* __restrict__ bnm, const float* __restrict__ bnv,
             f16_t* __restrict__ C)
{
    constexpr int NT  = NKB;                  // K-tiles of 32
    constexpr int NNT = N / 16;
    __shared__ f16_t sm[32768];               // 2 x 32 KB

    const int t = threadIdx.x;
    const int lane = t & 63, w = t >> 6;
    const int wm = w >> 2, wn = w & 3;        // 2M x 4N waves
    const int quad = lane >> 4, l16 = lane & 15;
    const int id = blockIdx.x;
    const int xi = id / NY, y = id - xi * NY;
    const int r0 = xi * 256;
    const int n0 = y * 256;
    const int rtg = r0 >> 4;
    const int nbase = n0 >> 4;
    const int segB = SEG ? seg_of(r0) : 0;
    const bool strad = SEG && (seg_of(r0 + 255) != segB);
    const int segw = SEG ? seg_of(r0 + wm*128) : 0;

    f32x4 acc[8][4];
#pragma unroll
    for (int mi = 0; mi < 8; ++mi)
#pragma unroll
        for (int ni = 0; ni < 4; ++ni) acc[mi][ni] = (f32x4){0.f,0.f,0.f,0.f};

    size_t aoff[2];
#pragma unroll
    for (int i = 0; i < 2; ++i)
        aoff[i] = (size_t)(r0 + (w*2 + i)*16 + l16) * LDA + quad*8;

    auto stage = [&](int kb, int buf) {
        f16_t* bb = sm + buf*16384;
#pragma unroll
        for (int i = 0; i < 2; ++i) {
            const int rt = w*2 + i;
            if constexpr (KSPB > 0) {
                if (kb < KSPB)
                    glds16(A0 + (size_t)kb*32 + aoff[i], bb + rt*512);
                else
                    glds16(A1 + ((size_t)(rtg + rt)*NKBA1 + (kb - KSPB))*512 + lane*8,
                           bb + rt*512);
            } else {
                glds16(A1 + ((size_t)(rtg + rt)*NKBA1 + kb)*512 + lane*8,
                       bb + rt*512);
            }
            glds16(Wp + ((size_t)(segB*NNT + nbase + rt)*NKB + kb)*512 + lane*8,
                   bb + 8192 + rt*512);
        }
    };

    stage(0, 0);
    __syncthreads();

    for (int kt = 0; kt < NT; ++kt) {
        const int buf = kt & 1;
        if (kt + 1 < NT) stage(kt + 1, buf ^ 1);    // prefetch overlaps compute
        const f16_t* bb = sm + buf*16384;

        half8 bfr[4];
        if (strad) {
#pragma unroll
            for (int ni = 0; ni < 4; ++ni)
                bfr[ni] = *(const half8*)(Wp +
                    ((size_t)(segw*NNT + nbase + wn*4 + ni)*NKB + kt)*512 + lane*8);
        } else {
#pragma unroll
            for (int ni = 0; ni < 4; ++ni)
                bfr[ni] = *(const half8*)(bb + 8192 + (wn*4 + ni)*512 + lane*8);
        }

#pragma unroll
        for (int ph = 0; ph < 4; ++ph) {
            half8 a[2];
#pragma unroll
            for (int m2 = 0; m2 < 2; ++m2)
                a[m2] = *(const half8*)(bb + (wm*8 + ph*2 + m2)*512 + lane*8);
#pragma unroll
            for (int m2 = 0; m2 < 2; ++m2)
#pragma unroll
                for (int ni = 0; ni < 4; ++ni)
                    acc[ph*2 + m2][ni] = __builtin_amdgcn_mfma_f32_16x16x32_f16(
                        a[m2], bfr[ni], acc[ph*2 + m2][ni], 0, 0, 0);
        }
        __syncthreads();
    }

    // epilogue: 4 strips of 64 rows via LDS, coalesced 16-B stores
    f16_t* eps = sm;
#pragma unroll
    for (int s = 0; s < 4; ++s) {
        if (wm == (s >> 1)) {
#pragma unroll
            for (int ni = 0; ni < 4; ++ni) {
                const int lcol = wn*64 + ni*16 + l16;
                const int col = n0 + lcol;
                const float scale = bng[col] * rsqrtf(bnv[col] + 1e-3f);
                const float shift = bnb[col] - bnm[col] * scale;
                const float bv = bias[(SEG ? segw*N : 0) + col];
#pragma unroll
                for (int m2 = 0; m2 < 4; ++m2) {
                    const int mi = (s & 1)*4 + m2;
                    const int rowb = m2*16 + quad*4;
#pragma unroll
                    for (int rr = 0; rr < 4; ++rr) {
                        float v = acc[mi][ni][rr] + bv;
                        v = fmaxf(v, 0.f);
                        v = fmaf(v, scale, shift);
                        eps[(rowb + rr)*264 + lcol] = (f16_t)v;
                    }
                }
            }
        }
        __syncthreads();
#pragma unroll
        for (int k = 0; k < 4; ++k) {
            int idx = k*512 + t;                    // 2048 uint4 = 64 rows x 32 chunks
            int row = idx >> 5, ch = idx & 31;
            *(uint4*)(C + (size_t)(r0 + s*64 + row)*N + n0 + ch*8) =
                *(const uint4*)&eps[row*264 + ch*8];
        }
        __syncthreads();
    }
}

// ---------------- dense GEMM: direct blob->register with REGISTER double-buffer ----------------
// R8/R9: VGPR_Count=64 starved MLP (loads serialized, 45us latency-bound). Explicit
// reg-dbuf: prefetch kb+1's 8 fragments while MFMA-ing kb; launch_bounds(256,2)
// lifts VGPR cap. All-static indexing (rule #20). XCD-grouped mapping kept (R7).
// Ascending-kb accumulation -> bitwise-same C.
__global__ __launch_bounds__(256, 2)
void gemm_dir(const f16_t* __restrict__ A, const f16_t* __restrict__ Wp,
              const float* __restrict__ bias,
              const float* __restrict__ bng, const float* __restrict__ bnb,
              const float* __restrict__ bnm, const float* __restrict__ bnv,
              f16_t* __restrict__ C)
{
    constexpr int NKB = 8, N = 512;
    __shared__ f16_t eps[128*136];                 // epilogue only (34.8 KB)
    const int t = threadIdx.x, lane = t & 63, w = t >> 6;
    const int wm = w >> 1, wn = w & 1;             // 2M x 2N waves
    const int quad = lane >> 4, l16 = lane & 15;
    const int id = blockIdx.x;                     // 2048 = 8 xcd x 64 xi x 4 y
    const int xcd = id & 7;
    const int j = id >> 3;
    const int xi = xcd * 64 + (j >> 2);
    const int y = j & 3;
    const int r0 = xi * 128, n0 = y * 128;
    const int rt0 = (r0 >> 4) + wm*4;
    const int nt0 = (n0 >> 4) + wn*4;

    f32x4 acc[4][4];
#pragma unroll
    for (int mi = 0; mi < 4; ++mi)
#pragma unroll
        for (int ni = 0; ni < 4; ++ni) acc[mi][ni] = (f32x4){0.f,0.f,0.f,0.f};

    const f16_t* ap = A  + (size_t)rt0 * NKB * 512 + lane*8;
    const f16_t* bp = Wp + (size_t)nt0 * NKB * 512 + lane*8;

    half8 aA[4], bA[4], aB[4], bB[4];
#pragma unroll
    for (int i = 0; i < 4; ++i) {
        aA[i] = *(const half8*)(ap + ((size_t)i*NKB + 0)*512);
        bA[i] = *(const half8*)(bp + ((size_t)i*NKB + 0)*512);
    }
#pragma unroll
    for (int kb = 0; kb < NKB; kb += 2) {
        if (kb + 1 < NKB) {
#pragma unroll
            for (int i = 0; i < 4; ++i) {
                aB[i] = *(const half8*)(ap + ((size_t)i*NKB + kb + 1)*512);
                bB[i] = *(const half8*)(bp + ((size_t)i*NKB + kb + 1)*512);
            }
        }
#pragma unroll
        for (int mi = 0; mi < 4; ++mi)
#pragma unroll
            for (int ni = 0; ni < 4; ++ni)
                acc[mi][ni] = __builtin_amdgcn_mfma_f32_16x16x32_f16(
                    aA[mi], bA[ni], acc[mi][ni], 0, 0, 0);
        if (kb + 2 < NKB) {
#pragma unroll
            for (int i = 0; i < 4; ++i) {
                aA[i] = *(const half8*)(ap + ((size_t)i*NKB + kb + 2)*512);
                bA[i] = *(const half8*)(bp + ((size_t)i*NKB + kb + 2)*512);
            }
        }
        if (kb + 1 < NKB) {
#pragma unroll
            for (int mi = 0; mi < 4; ++mi)
#pragma unroll
                for (int ni = 0; ni < 4; ++ni)
                    acc[mi][ni] = __builtin_amdgcn_mfma_f32_16x16x32_f16(
                        aB[mi], bB[ni], acc[mi][ni], 0, 0, 0);
        }
    }

    // epilogue: all 4 waves write disjoint quadrants, one sync, coalesced stores
#pragma unroll
    for (int ni = 0; ni < 4; ++ni) {
        const int lcol = wn*64 + ni*16 + l16;
        const int col = n0 + lcol;
        const float scale = bng[col] * rsqrtf(bnv[col] + 1e-3f);
        const float shift = bnb[col] - bnm[col] * scale;
        const float bv = bias[col];
#pragma unroll
        for (int mi = 0; mi < 4; ++mi) {
            const int rowb = wm*64 + mi*16 + quad*4;
#pragma unroll
            for (int rr = 0; rr < 4; ++rr) {
                float v = acc[mi][ni][rr] + bv;
                v = fmaxf(v, 0.f);
                v = fmaf(v, scale, shift);
                eps[(rowb + rr)*136 + lcol] = (f16_t)v;
            }
        }
    }
    __syncthreads();
#pragma unroll
    for (int k2 = 0; k2 < 8; ++k2) {
        int idx = k2*256 + t;                       // 2048 uint4 = 128 rows x 16 chunks
        int row = idx >> 4, ch = idx & 15;
        *(uint4*)(C + (size_t)(r0 + row)*N + n0 + ch*8) =
            *(const uint4*)&eps[row*136 + ch*8];
    }
}

// ---------------- segment sum/max over H3[65536x512] -> fp = tanh([ssum|smax]) ----------------
__global__ __launch_bounds__(256)
void reduce_k(const f16_t* __restrict__ H3, const int* __restrict__ slots,
              float* __restrict__ fp) {
    __shared__ float shs[3][512];
    __shared__ float shm[3][512];
    int s = blockIdx.x;
    int t = threadIdx.x;
    int w = t >> 6, l = t & 63;
    int c = l * 8;
    const int* sl = slots + s*32 + w*8;
    float sm[8], mx[8];
#pragma unroll
    for (int e = 0; e < 8; ++e) { sm[e] = 0.f; mx[e] = -INFINITY; }
#pragma unroll
    for (int i = 0; i < 8; ++i) {
        int a = sl[i];
        uint4 raw = *(const uint4*)(H3 + (size_t)a*512 + c);
        const f16_t* u = (const f16_t*)&raw;
#pragma unroll
        for (int e = 0; e < 8; ++e) {
            float f = (float)u[e];
            sm[e] += f;
            mx[e] = fmaxf(mx[e], f);
        }
    }
    if (w) {
        *(float4*)&shs[w-1][c]   = *(float4*)&sm[0];
        *(float4*)&shs[w-1][c+4] = *(float4*)&sm[4];
        *(float4*)&shm[w-1][c]   = *(float4*)&mx[0];
        *(float4*)&shm[w-1][c+4] = *(float4*)&mx[4];
    }
    __syncthreads();
    if (w == 0) {
#pragma unroll
        for (int j = 0; j < 3; ++j)
#pragma unroll
            for (int e = 0; e < 8; ++e) {
                sm[e] += shs[j][c+e];
                mx[e] = fmaxf(mx[e], shm[j][c+e]);
            }
        float o1[8], o2[8];
#pragma unroll
        for (int e = 0; e < 8; ++e) {
            o1[e] = tanhf(sm[e]); o2[e] = tanhf(mx[e]);
        }
        float* fr = fp + (size_t)s*1024;
        *(float4*)(fr + c)       = *(float4*)&o1[0];
        *(float4*)(fr + c + 4)   = *(float4*)&o1[4];
        *(float4*)(fr + 512 + c)     = *(float4*)&o2[0];
        *(float4*)(fr + 512 + c + 4) = *(float4*)&o2[4];
    }
}

// ---------------- readout GEMM: logits = fp @ out_w + out_b; probs = pair-softmax ----------------
__global__ __launch_bounds__(64)
void final_mfma(const float* __restrict__ fp, const f16_t* __restrict__ Wop,
                const float* __restrict__ out_b,
                float* __restrict__ probs, float* __restrict__ logits) {
    const int t = threadIdx.x;
    const int lane = t & 63;
    const int quad = lane >> 4, l16 = lane & 15;
    const int r0 = blockIdx.x * 16;

    f32x4 acc[2];
#pragma unroll
    for (int ni = 0; ni < 2; ++ni) acc[ni] = (f32x4){0.f,0.f,0.f,0.f};

    const size_t rowoff = (size_t)(r0 + l16) * 1024 + quad*8;
    size_t boff[2];
#pragma unroll
    for (int ni = 0; ni < 2; ++ni)
        boff[ni] = (size_t)ni * 32 * 512 + lane*8;

    auto loadA = [&](half8& a, int kb) {
        const float* src = fp + rowoff + kb*32;
        float4 u0 = *(const float4*)(src);
        float4 u1 = *(const float4*)(src + 4);
        half8 h;
        h[0] = (f16_t)u0.x; h[1] = (f16_t)u0.y; h[2] = (f16_t)u0.z; h[3] = (f16_t)u0.w;
        h[4] = (f16_t)u1.x; h[5] = (f16_t)u1.y; h[6] = (f16_t)u1.z; h[7] = (f16_t)u1.w;
        a = h;
    };
    auto loadB = [&](half8* b, int kb) {
#pragma unroll
        for (int ni = 0; ni < 2; ++ni) b[ni] = *(const half8*)(Wop + boff[ni] + (size_t)kb*512);
    };
    auto domfma = [&](half8& a, half8* b) {
#pragma unroll
        for (int ni = 0; ni < 2; ++ni)
            acc[ni] = __builtin_amdgcn_mfma_f32_16x16x32_f16(a, b[ni], acc[ni], 0, 0, 0);
    };

    half8 a0, b0[2], a1, b1[2];
    loadA(a0, 0); loadB(b0, 0);
#pragma unroll
    for (int kb = 0; kb < 32; kb += 2) {
        loadA(a1, kb + 1); loadB(b1, kb + 1);
        domfma(a0, b0);
        if (kb + 2 < 32) { loadA(a0, kb + 2); loadB(b0, kb + 2); }
        domfma(a1, b1);
    }

#pragma unroll
    for (int ni = 0; ni < 2; ++ni) {
        const int c = ni*16 + l16;
        const bool ok = (c < 24);
        const float bv = ok ? out_b[c] : 0.f;
#pragma unroll
        for (int r = 0; r < 4; ++r) {
            float lg = acc[ni][r] + bv;
            float lp = __shfl_xor(lg, 1);
            float m = fmaxf(lg, lp);
            float e  = expf(lg - m);
            float ep = expf(lp - m);
            float pr = e / (e + ep);
            if (ok) {
                int row = r0 + quad*4 + r;
                logits[(size_t)row*24 + c] = lg;
                probs[(size_t)row*24 + c]  = pr;
            }
        }
    }
}

extern "C" void kernel_launch(void* const* d_in, const int* in_sizes, int n_in,
                              void* d_out, int out_size, void* d_ws, size_t ws_size,
                              hipStream_t stream) {
    const float* atom       = (const float*)d_in[0];
    const int*   membership = (const int*)  d_in[2];
    Adj adj;
    for (int d = 0; d < 10; ++d) adj.p[d] = (const int*)d_in[4+d];
    const float* gc1_w0     = (const float*)d_in[14];
    const float* gc1_wself  = (const float*)d_in[15];
    const float* gc1_wneigh = (const float*)d_in[16];
    const float* gc1_b      = (const float*)d_in[17];
    const float* gc2_w0     = (const float*)d_in[18];
    const float* gc2_wself  = (const float*)d_in[19];
    const float* gc2_wneigh = (const float*)d_in[20];
    const float* gc2_b      = (const float*)d_in[21];
    const float* bn1g = (const float*)d_in[22]; const float* bn1b = (const float*)d_in[23];
    const float* bn1m = (const float*)d_in[24]; const float* bn1v = (const float*)d_in[25];
    const float* bn2g = (const float*)d_in[26]; const float* bn2b = (const float*)d_in[27];
    const float* bn2m = (const float*)d_in[28]; const float* bn2v = (const float*)d_in[29];
    const float* bn3g = (const float*)d_in[30]; const float* bn3b = (const float*)d_in[31];
    const float* bn3m = (const float*)d_in[32]; const float* bn3v = (const float*)d_in[33];
    const float* dense_w = (const float*)d_in[34];
    const float* dense_b = (const float*)d_in[35];
    const float* out_w   = (const float*)d_in[36];
    const float* out_b   = (const float*)d_in[37];

    // workspace (f16 units), single copies:
    f16_t* wsb = (f16_t*)d_ws;
    f16_t* xq    = wsb;                        //  6,291,456
    f16_t* NBX   = wsb + 6291456;              //  6,291,456 (blob NKB=3)
    f16_t* H1b   = wsb + 12582912;             // 16,777,216  (also H2; H3 starts here)
    f16_t* P1rm  = wsb + 29360128;             // 16,777,216
    f16_t* NB2b  = wsb + 46137344;             // 16,777,216 (blob NKB=8; later P2_bl)
    f16_t* H2b   = H1b;
    f16_t* P2bl  = NB2b;
    f16_t* H3b   = H1b;                        // 33,554,432 spans H1+P1rm
    f16_t* W1p   = wsb + 62914560;             //    540,672
    f16_t* W2p   = wsb + 63455232;             //  1,441,792
    f16_t* Wdp   = wsb + 64897024;             //    131,072
    f16_t* Wop   = wsb + 65028096;             //     32,768
    int*  counts = (int*)(wsb + 65060864);     // 2048 ints
    int*  slots  = counts + 2048;              // 65536 ints

    float* outp   = (float*)d_out;
    float* probs  = outp;            // 2048*24
    float* logits = outp + 49152;    // 2048*24
    float* fp     = outp + 98304;    // 2048*1024

    pack_cvt<<<11456, 256, 0, stream>>>(gc1_w0, gc1_wself, gc1_wneigh,
                                        gc2_w0, gc2_wself, gc2_wneigh,
                                        dense_w, out_w,
                                        W1p, W2p, Wdp, Wop, counts,
                                        atom, xq);

    // gc1: A0 = xq row-major (kb<3), A1 = NBX blob; 256 panels, NY=1
    nbsum_sc<<<3328, 256, 0, stream>>>(xq, NBX, adj, membership, counts, slots);
    gemm256<6,3,96,3,1,256,true><<<256, 512, 0, stream>>>(
        xq, NBX, W1p, gc1_b, bn1g, bn1b, bn1m, bn1v, H1b);
    pool_k<false><<<(NATOMS*32)/256, 256, 0, stream>>>(H1b, P1rm, adj);

    // gc2: A0 = P1rm row-major (kb<8), A1 = NB2 blob; 256 panels, NY=1
    nbsum_k<<<(NATOMS*32)/256, 256, 0, stream>>>(P1rm, NB2b, adj);
    gemm256<16,8,256,8,1,256,true><<<256, 512, 0, stream>>>(
        P1rm, NB2b, W2p, gc2_b, bn2g, bn2b, bn2m, bn2v, H2b);
    pool_k<true><<<(NATOMS*32)/256, 256, 0, stream>>>(H2b, P2bl, adj);

    // dense: direct blob->reg GEMM, reg-dbuf prefetch, XCD-grouped; 2048 x 256
    gemm_dir<<<2048, 256, 0, stream>>>(
        P2bl, Wdp, dense_b, bn3g, bn3b, bn3m, bn3v, H3b);

    // segment reduce + tanh -> fp (fp32, in d_out); 4 waves/segment
    reduce_k<<<2048, 256, 0, stream>>>(H3b, slots, fp);

    // readout
    final_mfma<<<128, 64, 0, stream>>>(fp, Wop, out_b, probs, logits);
}